// Round 1
// baseline (7230.553 us; speedup 1.0000x reference)
//
#include <hip/hip_runtime.h>
#include <hip/hip_bf16.h>

// ---------------- problem constants ----------------
#define LDIM   1851   // L = TT - TINI - NH + 1
#define NFR    1000   // rows of F = [Uf(400); Yf(600)]
#define NAR    506    // rows of A = [Up(200); Yp(300); Yf_last(6)]
#define NCRP   1536   // padded rows of C = [F; A]  (1506 -> 1536)
#define LDC    1856   // padded Hankel width        (1851 -> 1856)
#define NG     1024   // padded G dim               (1000 -> 1024)
#define NS     512    // padded S dim               (506  -> 512)
#define NXC    1152   // padded X12 cols            (600+506=1106 -> 1152)
#define LDMA   1120   // padded M_all cols          (1100 -> 1120)
#define NBATCH 4096
#define NOUT   1000
#define INVDP  500000.0   // 1/(2*DELTA)

// ---------------- ws layout (bytes) ----------------
#define OFF_C     ((size_t)0)
#define SZ_C      ((size_t)NCRP * LDC * 4)
#define OFF_GCC   (OFF_C + SZ_C)
#define SZ_GCC    ((size_t)NCRP * NCRP * 8)
#define OFF_G     (OFF_GCC + SZ_GCC)
#define SZ_G      ((size_t)NG * NG * 8)
#define OFF_TA    (OFF_G + SZ_G)
#define SZ_TA     ((size_t)NG * NS * 8)
#define OFF_S     (OFF_TA + SZ_TA)
#define SZ_S      ((size_t)NS * NS * 8)
#define OFF_X12   (OFF_S + SZ_S)
#define SZ_X12    ((size_t)NS * NXC * 8)
#define OFF_MRAW  (OFF_X12 + SZ_X12)
#define SZ_MRAW   ((size_t)NG * NXC * 4)
#define OFF_MALL  (OFF_MRAW + SZ_MRAW)
#define SZ_MALL   ((size_t)NG * LDMA * 4)
#define OFF_INALL (OFF_MALL + SZ_MALL)
#define SZ_INALL  ((size_t)LDMA * NBATCH * 4)
// total ~77.7 MB

__device__ __forceinline__ double dweight(int i, const float* q, const float* r) {
  return (i < 400) ? (double)r[i] : (double)q[i - 400];
}

// ---- 1) build C = [Uf; Yf; Up; Yp; Yf_last] (fp32, zero-padded) ----
__global__ __launch_bounds__(256) void k_build_C(const float* __restrict__ ud,
                                                 const float* __restrict__ yd,
                                                 float* __restrict__ C) {
  int j = blockIdx.x * 256 + threadIdx.x;
  int rr = blockIdx.y;
  if (j >= LDC) return;
  float v = 0.f;
  if (j < LDIM) {
    if (rr < 400)        v = ud[200 + rr + 4 * j];            // Uf
    else if (rr < 1000)  v = yd[300 + (rr - 400) + 6 * j];    // Yf
    else if (rr < 1200)  v = ud[(rr - 1000) + 4 * j];         // Up
    else if (rr < 1500)  v = yd[(rr - 1200) + 6 * j];         // Yp
    else if (rr < 1506)  v = yd[894 + (rr - 1500) + 6 * j];   // Yf[-P:]
  }
  C[(size_t)rr * LDC + j] = v;
}

// ---- 2) GCC = C * C^T, fp64 accumulation (lower tiles + mirror) ----
__global__ __launch_bounds__(256) void k_gram(const float* __restrict__ C,
                                              double* __restrict__ GCC) {
  int ti = blockIdx.y, tj = blockIdx.x;
  if (ti < tj) return;
  __shared__ float As[64][33];
  __shared__ float Bs[64][33];
  int tid = threadIdx.x;
  int tr4 = (tid >> 4) * 4, tc4 = (tid & 15) * 4;
  double acc[4][4] = {};
  int i0 = ti * 64, j0 = tj * 64;
  for (int k0 = 0; k0 < LDC; k0 += 32) {
#pragma unroll
    for (int l = 0; l < 8; ++l) {
      int t = tid + l * 256;
      int rr = t >> 5, cc = t & 31;
      As[rr][cc] = C[(size_t)(i0 + rr) * LDC + k0 + cc];
      Bs[rr][cc] = C[(size_t)(j0 + rr) * LDC + k0 + cc];
    }
    __syncthreads();
#pragma unroll
    for (int kk = 0; kk < 32; ++kk) {
      double a[4], b[4];
#pragma unroll
      for (int i = 0; i < 4; ++i) a[i] = (double)As[tr4 + i][kk];
#pragma unroll
      for (int jx = 0; jx < 4; ++jx) b[jx] = (double)Bs[tc4 + jx][kk];
#pragma unroll
      for (int i = 0; i < 4; ++i)
#pragma unroll
        for (int jx = 0; jx < 4; ++jx) acc[i][jx] += a[i] * b[jx];
    }
    __syncthreads();
  }
#pragma unroll
  for (int i = 0; i < 4; ++i)
#pragma unroll
    for (int jx = 0; jx < 4; ++jx) {
      int gi = i0 + tr4 + i, gj = j0 + tc4 + jx;
      GCC[(size_t)gi * NCRP + gj] = acc[i][jx];
      if (ti != tj) GCC[(size_t)gj * NCRP + gi] = acc[i][jx];
    }
}

// ---- 3) G = GFF + (1e-6/d) I, padded with identity ----
__global__ __launch_bounds__(256) void k_copyG(const double* __restrict__ GCC,
                                               const float* __restrict__ q,
                                               const float* __restrict__ r,
                                               double* __restrict__ G) {
  int idx = blockIdx.x * 256 + threadIdx.x;
  int i = idx >> 10, j = idx & 1023;
  double v = (i < NFR && j < NFR) ? GCC[(size_t)i * NCRP + j] : 0.0;
  if (i == j) {
    if (i < NFR) v += 1e-6 / dweight(i, q, r);
    else v = 1.0;
  }
  G[idx] = v;
}

// ---- 4) TA rhs = GAF^T = F A^T (padded zeros) ----
__global__ __launch_bounds__(256) void k_copyTA(const double* __restrict__ GCC,
                                                double* __restrict__ TA) {
  int idx = blockIdx.x * 256 + threadIdx.x;
  int f = idx >> 9, a = idx & 511;
  TA[idx] = (f < NFR && a < NAR) ? GCC[(size_t)f * NCRP + 1000 + a] : 0.0;
}

// ---- blocked fp64 Cholesky (lower), panel = 64 ----
__global__ __launch_bounds__(256) void k_potrf(double* __restrict__ M, int ld, int k) {
  __shared__ double T[64][65];
  int tid = threadIdx.x;
#pragma unroll
  for (int l = 0; l < 16; ++l) {
    int t = tid + l * 256;
    T[t >> 6][t & 63] = M[(size_t)(k + (t >> 6)) * ld + k + (t & 63)];
  }
  __syncthreads();
  for (int c = 0; c < 64; ++c) {
    if (tid == 0) T[c][c] = sqrt(T[c][c]);
    __syncthreads();
    double piv = T[c][c];
    for (int rr = c + 1 + tid; rr < 64; rr += 256) T[rr][c] /= piv;
    __syncthreads();
    for (int t = tid; t < 64 * 64; t += 256) {
      int rr = t >> 6, jj = t & 63;
      if (rr > c && jj > c) T[rr][jj] -= T[rr][c] * T[jj][c];
    }
    __syncthreads();
  }
#pragma unroll
  for (int l = 0; l < 16; ++l) {
    int t = tid + l * 256;
    M[(size_t)(k + (t >> 6)) * ld + k + (t & 63)] = T[t >> 6][t & 63];
  }
}

// panel TRSM: rows below solve  L21 = A21 * L11^{-T}; rows kept in registers
__global__ __launch_bounds__(256) void k_chol_trsm(double* __restrict__ M, int ld, int k) {
  __shared__ double L11[64][65];
  __shared__ double xs[64];
  int tid = threadIdx.x;
  int rr = tid & 63, g = tid >> 6;  // row, col-group (4 groups x 16 cols)
#pragma unroll
  for (int l = 0; l < 16; ++l) {
    int t = tid + l * 256;
    L11[t >> 6][t & 63] = M[(size_t)(k + (t >> 6)) * ld + k + (t & 63)];
  }
  int r0 = k + 64 + blockIdx.x * 64;
  double a[16];
#pragma unroll
  for (int cc = 0; cc < 16; ++cc) a[cc] = M[(size_t)(r0 + rr) * ld + k + g * 16 + cc];
  __syncthreads();
  for (int c = 0; c < 64; ++c) {
    if (g == (c >> 4)) {
      double x = a[c & 15] / L11[c][c];
      a[c & 15] = x;
      xs[rr] = x;
    }
    __syncthreads();
    double x = xs[rr];
#pragma unroll
    for (int cc = 0; cc < 16; ++cc) {
      int j = g * 16 + cc;
      if (j > c) a[cc] -= x * L11[j][c];
    }
    __syncthreads();
  }
#pragma unroll
  for (int cc = 0; cc < 16; ++cc) M[(size_t)(r0 + rr) * ld + k + g * 16 + cc] = a[cc];
}

// SYRK trailing update: A22 -= L21 * L21^T (lower tiles only)
__global__ __launch_bounds__(256) void k_chol_syrk(double* __restrict__ M, int ld, int k) {
  int ti = blockIdx.y, tj = blockIdx.x;
  if (ti < tj) return;
  __shared__ double Pa[64][33];
  __shared__ double Pb[64][33];
  int tid = threadIdx.x;
  int tr4 = (tid >> 4) * 4, tc4 = (tid & 15) * 4;
  int i0 = k + 64 + ti * 64, j0 = k + 64 + tj * 64;
  double acc[4][4] = {};
  for (int k0 = 0; k0 < 64; k0 += 32) {
#pragma unroll
    for (int l = 0; l < 8; ++l) {
      int t = tid + l * 256;
      int rr = t >> 5, cc = t & 31;
      Pa[rr][cc] = M[(size_t)(i0 + rr) * ld + k + k0 + cc];
      Pb[rr][cc] = M[(size_t)(j0 + rr) * ld + k + k0 + cc];
    }
    __syncthreads();
#pragma unroll
    for (int kk = 0; kk < 32; ++kk) {
      double a[4], b[4];
#pragma unroll
      for (int i = 0; i < 4; ++i) a[i] = Pa[tr4 + i][kk];
#pragma unroll
      for (int jx = 0; jx < 4; ++jx) b[jx] = Pb[tc4 + jx][kk];
#pragma unroll
      for (int i = 0; i < 4; ++i)
#pragma unroll
        for (int jx = 0; jx < 4; ++jx) acc[i][jx] += a[i] * b[jx];
    }
    __syncthreads();
  }
#pragma unroll
  for (int i = 0; i < 4; ++i)
#pragma unroll
    for (int jx = 0; jx < 4; ++jx)
      M[(size_t)(i0 + tr4 + i) * ld + j0 + tc4 + jx] -= acc[i][jx];
}

// ---- triangular solves with many RHS, blocked 64 ----
// forward: solve L_kk * X_k = X_k   (cols in registers)
__global__ __launch_bounds__(256) void k_trsm_fwd(const double* __restrict__ LM, int ldl, int k,
                                                  double* __restrict__ X, int ldx) {
  __shared__ double L11[64][65];
  __shared__ double xsh[64];
  int tid = threadIdx.x;
  int lane = tid & 63, g = tid >> 6;  // column-in-chunk, row-group
#pragma unroll
  for (int l = 0; l < 16; ++l) {
    int t = tid + l * 256;
    L11[t >> 6][t & 63] = LM[(size_t)(k + (t >> 6)) * ldl + k + (t & 63)];
  }
  int c0 = blockIdx.x * 64;
  double x[16];
#pragma unroll
  for (int ri = 0; ri < 16; ++ri) x[ri] = X[(size_t)(k + g * 16 + ri) * ldx + c0 + lane];
  __syncthreads();
  for (int r = 0; r < 64; ++r) {
    if (g == (r >> 4)) {
      double v = x[r & 15] / L11[r][r];
      x[r & 15] = v;
      xsh[lane] = v;
    }
    __syncthreads();
    double v = xsh[lane];
#pragma unroll
    for (int ri = 0; ri < 16; ++ri) {
      int rr = g * 16 + ri;
      if (rr > r) x[ri] -= L11[rr][r] * v;
    }
    __syncthreads();
  }
#pragma unroll
  for (int ri = 0; ri < 16; ++ri) X[(size_t)(k + g * 16 + ri) * ldx + c0 + lane] = x[ri];
}

// backward: solve L_kk^T * X_k = X_k
__global__ __launch_bounds__(256) void k_trsm_bwd(const double* __restrict__ LM, int ldl, int k,
                                                  double* __restrict__ X, int ldx) {
  __shared__ double L11[64][65];
  __shared__ double xsh[64];
  int tid = threadIdx.x;
  int lane = tid & 63, g = tid >> 6;
#pragma unroll
  for (int l = 0; l < 16; ++l) {
    int t = tid + l * 256;
    L11[t >> 6][t & 63] = LM[(size_t)(k + (t >> 6)) * ldl + k + (t & 63)];
  }
  int c0 = blockIdx.x * 64;
  double x[16];
#pragma unroll
  for (int ri = 0; ri < 16; ++ri) x[ri] = X[(size_t)(k + g * 16 + ri) * ldx + c0 + lane];
  __syncthreads();
  for (int r = 63; r >= 0; --r) {
    if (g == (r >> 4)) {
      double v = x[r & 15] / L11[r][r];
      x[r & 15] = v;
      xsh[lane] = v;
    }
    __syncthreads();
    double v = xsh[lane];
#pragma unroll
    for (int ri = 0; ri < 16; ++ri) {
      int rr = g * 16 + ri;
      if (rr < r) x[ri] -= L11[r][rr] * v;
    }
    __syncthreads();
  }
#pragma unroll
  for (int ri = 0; ri < 16; ++ri) X[(size_t)(k + g * 16 + ri) * ldx + c0 + lane] = x[ri];
}

// forward update: X[below] -= L[below, k-block] * X[k-block]
__global__ __launch_bounds__(256) void k_trsm_upd_fwd(const double* __restrict__ LM, int ldl, int k,
                                                      double* __restrict__ X, int ldx) {
  __shared__ double Ls[64][33];
  __shared__ double Xs[32][65];
  int tid = threadIdx.x;
  int tr4 = (tid >> 4) * 4, tc4 = (tid & 15) * 4;
  int r0 = k + 64 + blockIdx.y * 64;
  int c0 = blockIdx.x * 64;
  double acc[4][4] = {};
  for (int kc = 0; kc < 64; kc += 32) {
#pragma unroll
    for (int l = 0; l < 8; ++l) {
      int t = tid + l * 256;
      int rr = t >> 5, cc = t & 31;
      Ls[rr][cc] = LM[(size_t)(r0 + rr) * ldl + k + kc + cc];
    }
#pragma unroll
    for (int l = 0; l < 8; ++l) {
      int t = tid + l * 256;
      int rr = t >> 6, cc = t & 63;
      Xs[rr][cc] = X[(size_t)(k + kc + rr) * ldx + c0 + cc];
    }
    __syncthreads();
#pragma unroll
    for (int kk = 0; kk < 32; ++kk) {
      double a[4], b[4];
#pragma unroll
      for (int i = 0; i < 4; ++i) a[i] = Ls[tr4 + i][kk];
#pragma unroll
      for (int jx = 0; jx < 4; ++jx) b[jx] = Xs[kk][tc4 + jx];
#pragma unroll
      for (int i = 0; i < 4; ++i)
#pragma unroll
        for (int jx = 0; jx < 4; ++jx) acc[i][jx] += a[i] * b[jx];
    }
    __syncthreads();
  }
#pragma unroll
  for (int i = 0; i < 4; ++i)
#pragma unroll
    for (int jx = 0; jx < 4; ++jx)
      X[(size_t)(r0 + tr4 + i) * ldx + c0 + tc4 + jx] -= acc[i][jx];
}

// backward update: X[above] -= L^T[above, k-block] * X[k-block]  (L read transposed)
__global__ __launch_bounds__(256) void k_trsm_upd_bwd(const double* __restrict__ LM, int ldl, int k,
                                                      double* __restrict__ X, int ldx) {
  __shared__ double Ls[32][65];
  __shared__ double Xs[32][65];
  int tid = threadIdx.x;
  int tr4 = (tid >> 4) * 4, tc4 = (tid & 15) * 4;
  int r0 = blockIdx.y * 64;  // rows above (r0+64 <= k)
  int c0 = blockIdx.x * 64;
  double acc[4][4] = {};
  for (int kc = 0; kc < 64; kc += 32) {
#pragma unroll
    for (int l = 0; l < 8; ++l) {
      int t = tid + l * 256;
      int jj = t >> 6, rr = t & 63;
      Ls[jj][rr] = LM[(size_t)(k + kc + jj) * ldl + r0 + rr];
    }
#pragma unroll
    for (int l = 0; l < 8; ++l) {
      int t = tid + l * 256;
      int rr = t >> 6, cc = t & 63;
      Xs[rr][cc] = X[(size_t)(k + kc + rr) * ldx + c0 + cc];
    }
    __syncthreads();
#pragma unroll
    for (int kk = 0; kk < 32; ++kk) {
      double a[4], b[4];
#pragma unroll
      for (int i = 0; i < 4; ++i) a[i] = Ls[kk][tr4 + i];
#pragma unroll
      for (int jx = 0; jx < 4; ++jx) b[jx] = Xs[kk][tc4 + jx];
#pragma unroll
      for (int i = 0; i < 4; ++i)
#pragma unroll
        for (int jx = 0; jx < 4; ++jx) acc[i][jx] += a[i] * b[jx];
    }
    __syncthreads();
  }
#pragma unroll
  for (int i = 0; i < 4; ++i)
#pragma unroll
    for (int jx = 0; jx < 4; ++jx)
      X[(size_t)(r0 + tr4 + i) * ldx + c0 + tc4 + jx] -= acc[i][jx];
}

// ---- S = (GAA - GAF * TA) / (2*DELTA), identity-padded ----
__global__ __launch_bounds__(256) void k_buildS(const double* __restrict__ GCC,
                                                const double* __restrict__ TA,
                                                double* __restrict__ S) {
  __shared__ double Ga[64][33];
  __shared__ double Tb[32][65];
  int tid = threadIdx.x;
  int tr4 = (tid >> 4) * 4, tc4 = (tid & 15) * 4;
  int a0 = blockIdx.y * 64, b0 = blockIdx.x * 64;
  double acc[4][4] = {};
  for (int f0 = 0; f0 < NG; f0 += 32) {
#pragma unroll
    for (int l = 0; l < 8; ++l) {
      int t = tid + l * 256;
      int rr = t >> 5, cc = t & 31;
      Ga[rr][cc] = GCC[(size_t)(1000 + a0 + rr) * NCRP + f0 + cc];
    }
#pragma unroll
    for (int l = 0; l < 8; ++l) {
      int t = tid + l * 256;
      int rr = t >> 6, cc = t & 63;
      Tb[rr][cc] = TA[(size_t)(f0 + rr) * NS + b0 + cc];
    }
    __syncthreads();
#pragma unroll
    for (int kk = 0; kk < 32; ++kk) {
      double a[4], b[4];
#pragma unroll
      for (int i = 0; i < 4; ++i) a[i] = Ga[tr4 + i][kk];
#pragma unroll
      for (int jx = 0; jx < 4; ++jx) b[jx] = Tb[kk][tc4 + jx];
#pragma unroll
      for (int i = 0; i < 4; ++i)
#pragma unroll
        for (int jx = 0; jx < 4; ++jx) acc[i][jx] += a[i] * b[jx];
    }
    __syncthreads();
  }
#pragma unroll
  for (int i = 0; i < 4; ++i)
#pragma unroll
    for (int jx = 0; jx < 4; ++jx) {
      int a = a0 + tr4 + i, b = b0 + tc4 + jx;
      double v;
      if (a < NAR && b < NAR)
        v = (GCC[(size_t)(1000 + a) * NCRP + 1000 + b] - acc[i][jx]) * INVDP;
      else
        v = (a == b) ? 1.0 : 0.0;
      S[(size_t)a * NS + b] = v;
    }
}

// ---- X12 rhs = [TAq^T | I] ----
__global__ __launch_bounds__(256) void k_build_x12rhs(const double* __restrict__ TA,
                                                      double* __restrict__ X12) {
  int c = blockIdx.x * 256 + threadIdx.x;
  int a = blockIdx.y;
  if (c >= NXC) return;
  double v = 0.0;
  if (a < NAR) {
    if (c < 600) v = TA[(size_t)(400 + c) * NS + a];
    else if (c < 1106) v = (a == (c - 600)) ? 1.0 : 0.0;
  }
  X12[(size_t)a * NXC + c] = v;
}

// ---- Mraw = sign * (TA * X12) / (2 d_o)  (fp32 output) ----
__global__ __launch_bounds__(256) void k_gemm_M(const double* __restrict__ TA,
                                                const double* __restrict__ X12,
                                                const float* __restrict__ q,
                                                const float* __restrict__ r,
                                                float* __restrict__ Mraw) {
  __shared__ double Ga[64][33];
  __shared__ double Xb[32][65];
  int tid = threadIdx.x;
  int tr4 = (tid >> 4) * 4, tc4 = (tid & 15) * 4;
  int o0 = blockIdx.y * 64, c0 = blockIdx.x * 64;
  double acc[4][4] = {};
  for (int k0 = 0; k0 < NS; k0 += 32) {
#pragma unroll
    for (int l = 0; l < 8; ++l) {
      int t = tid + l * 256;
      int rr = t >> 5, cc = t & 31;
      Ga[rr][cc] = TA[(size_t)(o0 + rr) * NS + k0 + cc];
    }
#pragma unroll
    for (int l = 0; l < 8; ++l) {
      int t = tid + l * 256;
      int rr = t >> 6, cc = t & 63;
      Xb[rr][cc] = X12[(size_t)(k0 + rr) * NXC + c0 + cc];
    }
    __syncthreads();
#pragma unroll
    for (int kk = 0; kk < 32; ++kk) {
      double a[4], b[4];
#pragma unroll
      for (int i = 0; i < 4; ++i) a[i] = Ga[tr4 + i][kk];
#pragma unroll
      for (int jx = 0; jx < 4; ++jx) b[jx] = Xb[kk][tc4 + jx];
#pragma unroll
      for (int i = 0; i < 4; ++i)
#pragma unroll
        for (int jx = 0; jx < 4; ++jx) acc[i][jx] += a[i] * b[jx];
    }
    __syncthreads();
  }
#pragma unroll
  for (int i = 0; i < 4; ++i)
#pragma unroll
    for (int jx = 0; jx < 4; ++jx) {
      int o = o0 + tr4 + i, col = c0 + tc4 + jx;
      float v = 0.f;
      if (o < NFR) {
        double scale = 1.0 / (2.0 * dweight(o, q, r));
        double t = acc[i][jx] * scale;
        v = (float)((col < 600) ? -t : t);
      }
      Mraw[(size_t)o * NXC + col] = v;
    }
}

// ---- assemble final fp32 map: identity insert + ref_last fold ----
__global__ __launch_bounds__(256) void k_assemble_M(const float* __restrict__ Mraw,
                                                    float* __restrict__ Mall) {
  int j = blockIdx.x * 256 + threadIdx.x;
  int o = blockIdx.y;
  if (j >= LDMA) return;
  float v = 0.f;
  if (j < 600) {
    v = Mraw[(size_t)o * NXC + j];
    if (o == 400 + j) v += 1.0f;
    if (j >= 594) v += Mraw[(size_t)o * NXC + 1100 + (j - 594)];
  } else if (j < 1100) {
    v = Mraw[(size_t)o * NXC + j];
  }
  Mall[(size_t)o * LDMA + j] = v;
}

// ---- transpose batch inputs into IN_all [LDMA][NBATCH] ----
__global__ __launch_bounds__(256) void k_transpose_in(const float* __restrict__ ref,
                                                      const float* __restrict__ ui,
                                                      const float* __restrict__ yi,
                                                      float* __restrict__ INall) {
  __shared__ float t[32][33];
  int tx = threadIdx.x & 31, ty = threadIdx.x >> 5;  // 32 x 8
  int n0 = blockIdx.x * 32, j0 = blockIdx.y * 32;
#pragma unroll
  for (int p = 0; p < 4; ++p) {
    int nb = n0 + ty + p * 8;
    int j = j0 + tx;
    float v = 0.f;
    if (j < 600)        v = ref[(size_t)nb * 600 + j];
    else if (j < 800)   v = ui[(size_t)nb * 200 + (j - 600)];
    else if (j < 1100)  v = yi[(size_t)nb * 300 + (j - 800)];
    t[ty + p * 8][tx] = v;
  }
  __syncthreads();
#pragma unroll
  for (int p = 0; p < 4; ++p) {
    INall[(size_t)(j0 + ty + p * 8) * NBATCH + n0 + tx] = t[tx][ty + p * 8];
  }
}

// ---- final batch GEMM: OUT[1000][4096] = Mall[1000][1120] * INall[1120][4096] ----
__global__ __launch_bounds__(256) void k_gemm_out(const float* __restrict__ Mall,
                                                  const float* __restrict__ INall,
                                                  float* __restrict__ out) {
  __shared__ float As[32][132];  // k-major A tile (128 rows)
  __shared__ float Bs[32][132];  // k-major B tile (128 cols)
  int tid = threadIdx.x;
  int tr = tid >> 4, tc = tid & 15;
  int m0 = blockIdx.y * 128, n0 = blockIdx.x * 128;
  float acc[8][8] = {};
  for (int k0 = 0; k0 < LDMA; k0 += 32) {
#pragma unroll
    for (int l = 0; l < 16; ++l) {
      int t = tid + l * 256;
      int rr = t >> 5, cc = t & 31;
      As[cc][rr] = Mall[(size_t)(m0 + rr) * LDMA + k0 + cc];
    }
#pragma unroll
    for (int l = 0; l < 16; ++l) {
      int t = tid + l * 256;
      int rr = t >> 7, cc = t & 127;
      Bs[rr][cc] = INall[(size_t)(k0 + rr) * NBATCH + n0 + cc];
    }
    __syncthreads();
#pragma unroll
    for (int kk = 0; kk < 32; ++kk) {
      float4 a0 = *(const float4*)&As[kk][tr * 4];
      float4 a1 = *(const float4*)&As[kk][64 + tr * 4];
      float4 b0 = *(const float4*)&Bs[kk][tc * 4];
      float4 b1 = *(const float4*)&Bs[kk][64 + tc * 4];
      float av[8] = {a0.x, a0.y, a0.z, a0.w, a1.x, a1.y, a1.z, a1.w};
      float bv[8] = {b0.x, b0.y, b0.z, b0.w, b1.x, b1.y, b1.z, b1.w};
#pragma unroll
      for (int i = 0; i < 8; ++i)
#pragma unroll
        for (int jx = 0; jx < 8; ++jx) acc[i][jx] += av[i] * bv[jx];
    }
    __syncthreads();
  }
#pragma unroll
  for (int ih = 0; ih < 2; ++ih)
#pragma unroll
    for (int i = 0; i < 4; ++i) {
      int o = m0 + ih * 64 + tr * 4 + i;
      if (o < NOUT) {
#pragma unroll
        for (int jh = 0; jh < 2; ++jh) {
          float4 v = make_float4(acc[ih * 4 + i][jh * 4 + 0], acc[ih * 4 + i][jh * 4 + 1],
                                 acc[ih * 4 + i][jh * 4 + 2], acc[ih * 4 + i][jh * 4 + 3]);
          *(float4*)&out[(size_t)o * NBATCH + n0 + jh * 64 + tc * 4] = v;
        }
      }
    }
}

extern "C" void kernel_launch(void* const* d_in, const int* in_sizes, int n_in,
                              void* d_out, int out_size, void* d_ws, size_t ws_size,
                              hipStream_t stream) {
  const float* ud  = (const float*)d_in[0];
  const float* yd  = (const float*)d_in[1];
  const float* qv  = (const float*)d_in[2];
  const float* rv  = (const float*)d_in[3];
  const float* ref = (const float*)d_in[4];
  const float* ui  = (const float*)d_in[5];
  const float* yi  = (const float*)d_in[6];
  float* out = (float*)d_out;
  char* w = (char*)d_ws;

  float*  C    = (float*)(w + OFF_C);
  double* GCC  = (double*)(w + OFF_GCC);
  double* G    = (double*)(w + OFF_G);
  double* TA   = (double*)(w + OFF_TA);
  double* S    = (double*)(w + OFF_S);
  double* X12  = (double*)(w + OFF_X12);
  float*  MRAW = (float*)(w + OFF_MRAW);
  float*  MALL = (float*)(w + OFF_MALL);
  float*  INA  = (float*)(w + OFF_INALL);

  // 1) Hankel blocks, Gram, G and T_A rhs
  k_build_C<<<dim3(8, NCRP), 256, 0, stream>>>(ud, yd, C);
  k_gram<<<dim3(24, 24), 256, 0, stream>>>(C, GCC);
  k_copyG<<<dim3(NG * NG / 256), 256, 0, stream>>>(GCC, qv, rv, G);
  k_copyTA<<<dim3(NG * NS / 256), 256, 0, stream>>>(GCC, TA);

  // 2) Cholesky of G (1024, padded)
  for (int k = 0; k < NG; k += 64) {
    k_potrf<<<1, 256, 0, stream>>>(G, NG, k);
    int nb = (NG - k - 64) / 64;
    if (nb > 0) {
      k_chol_trsm<<<dim3(nb), 256, 0, stream>>>(G, NG, k);
      k_chol_syrk<<<dim3(nb, nb), 256, 0, stream>>>(G, NG, k);
    }
  }
  // 3) T_A = G^{-1} GAF^T  (fwd then bwd)
  for (int k = 0; k < NG; k += 64) {
    k_trsm_fwd<<<dim3(NS / 64), 256, 0, stream>>>(G, NG, k, TA, NS);
    int nb = (NG - k - 64) / 64;
    if (nb > 0) k_trsm_upd_fwd<<<dim3(NS / 64, nb), 256, 0, stream>>>(G, NG, k, TA, NS);
  }
  for (int k = NG - 64; k >= 0; k -= 64) {
    k_trsm_bwd<<<dim3(NS / 64), 256, 0, stream>>>(G, NG, k, TA, NS);
    if (k > 0) k_trsm_upd_bwd<<<dim3(NS / 64, k / 64), 256, 0, stream>>>(G, NG, k, TA, NS);
  }

  // 4) S and its Cholesky (512, padded)
  k_buildS<<<dim3(8, 8), 256, 0, stream>>>(GCC, TA, S);
  for (int k = 0; k < NS; k += 64) {
    k_potrf<<<1, 256, 0, stream>>>(S, NS, k);
    int nb = (NS - k - 64) / 64;
    if (nb > 0) {
      k_chol_trsm<<<dim3(nb), 256, 0, stream>>>(S, NS, k);
      k_chol_syrk<<<dim3(nb, nb), 256, 0, stream>>>(S, NS, k);
    }
  }

  // 5) X12 = S^{-1} [TAq^T | I]
  k_build_x12rhs<<<dim3(5, NS), 256, 0, stream>>>(TA, X12);
  for (int k = 0; k < NS; k += 64) {
    k_trsm_fwd<<<dim3(NXC / 64), 256, 0, stream>>>(S, NS, k, X12, NXC);
    int nb = (NS - k - 64) / 64;
    if (nb > 0) k_trsm_upd_fwd<<<dim3(NXC / 64, nb), 256, 0, stream>>>(S, NS, k, X12, NXC);
  }
  for (int k = NS - 64; k >= 0; k -= 64) {
    k_trsm_bwd<<<dim3(NXC / 64), 256, 0, stream>>>(S, NS, k, X12, NXC);
    if (k > 0) k_trsm_upd_bwd<<<dim3(NXC / 64, k / 64), 256, 0, stream>>>(S, NS, k, X12, NXC);
  }

  // 6) solution maps + batch GEMM
  k_gemm_M<<<dim3(NXC / 64, NG / 64), 256, 0, stream>>>(TA, X12, qv, rv, MRAW);
  k_assemble_M<<<dim3(5, NG), 256, 0, stream>>>(MRAW, MALL);
  k_transpose_in<<<dim3(NBATCH / 32, LDMA / 32), 256, 0, stream>>>(ref, ui, yi, INA);
  k_gemm_out<<<dim3(NBATCH / 128, NG / 128), 256, 0, stream>>>(MALL, INA, out);
}

// Round 2
// 5103.618 us; speedup vs baseline: 1.4168x; 1.4168x over previous
//
#include <hip/hip_runtime.h>
#include <hip/hip_bf16.h>

// ---------------- problem constants ----------------
#define LDIM   1851   // L = TT - TINI - NH + 1
#define NFR    1000   // rows of F = [Uf(400); Yf(600)]
#define NAR    506    // rows of A = [Up(200); Yp(300); Yf_last(6)]
#define NCRP   1536   // padded rows of C = [F; A]
#define LDC    1856   // padded Hankel width
#define NG     1024   // padded G dim
#define NS     512    // padded S dim
#define NXC    1152   // padded X12 cols (1106 -> 1152)
#define LDMA   1120   // padded M_all cols (1100 -> 1120)
#define NBATCH 4096
#define NOUT   1000
#define INVDP  500000.0   // 1/(2*DELTA)

// ---------------- ws layout (bytes), lifetime-overlaid, total ~77.3 MB ----------------
#define OFF_C     ((size_t)0)
#define SZ_C      ((size_t)NCRP * LDC * 4)            // 11,403,264 ; C dead after k_gram
#define OFF_ILG   OFF_C                               // 1024*1024*8 = 8,388,608 (over C)
#define OFF_ILS   (OFF_C + 8388608)                   // 512*512*8 = 2,097,152 (over C)
#define OFF_GCC   (OFF_C + SZ_C)
#define SZ_GCC    ((size_t)NCRP * NCRP * 8)
#define OFF_G     (OFF_GCC + SZ_GCC)
#define SZ_G      ((size_t)NG * NG * 8)
#define OFF_TA    (OFF_G + SZ_G)
#define SZ_TA     ((size_t)NG * NS * 8)
#define OFF_S     (OFF_TA + SZ_TA)
#define SZ_S      ((size_t)NS * NS * 8)
#define OFF_X12   (OFF_S + SZ_S)
#define SZ_X12    ((size_t)NS * NXC * 8)
#define OFF_MRAW  (OFF_X12 + SZ_X12)
#define SZ_MRAW   ((size_t)NG * NXC * 4)              // 4,718,592
#define OFF_XB    OFF_MRAW                            // 512*1152*8 = 4,718,592 (XB dead before MRAW written)
#define OFF_MALL  (OFF_MRAW + SZ_MRAW)
#define SZ_MALL   ((size_t)NG * LDMA * 4)             // 4,587,520 ; written at end
#define OFF_IDG   OFF_MALL                            // 16*64*64*8 = 524,288 (dead before MALL)
#define OFF_IDS   (OFF_MALL + 524288)                 // 8*64*64*8 = 262,144
#define OFF_INALL (OFF_MALL + SZ_MALL)
#define SZ_INALL  ((size_t)LDMA * NBATCH * 4)         // 18,350,080 ; written late by transpose
#define OFF_TB    OFF_INALL                           // 1024*512*8 = 4,194,304 (dead before transpose)
#define OFF_TINV  (OFF_INALL + 4194304)               // 512*512*8 = 2,097,152 (dead before transpose)

__device__ __forceinline__ double dweight(int i, const float* q, const float* r) {
  return (i < 400) ? (double)r[i] : (double)q[i - 400];
}

// ---- 1) build C = [Uf; Yf; Up; Yp; Yf_last] (fp32, zero-padded) ----
__global__ __launch_bounds__(256) void k_build_C(const float* __restrict__ ud,
                                                 const float* __restrict__ yd,
                                                 float* __restrict__ C) {
  int j = blockIdx.x * 256 + threadIdx.x;
  int rr = blockIdx.y;
  if (j >= LDC) return;
  float v = 0.f;
  if (j < LDIM) {
    if (rr < 400)        v = ud[200 + rr + 4 * j];            // Uf
    else if (rr < 1000)  v = yd[300 + (rr - 400) + 6 * j];    // Yf
    else if (rr < 1200)  v = ud[(rr - 1000) + 4 * j];         // Up
    else if (rr < 1500)  v = yd[(rr - 1200) + 6 * j];         // Yp
    else if (rr < 1506)  v = yd[894 + (rr - 1500) + 6 * j];   // Yf[-P:]
  }
  C[(size_t)rr * LDC + j] = v;
}

// ---- 2) GCC = C * C^T, fp64 accumulation (lower tiles + mirror) ----
__global__ __launch_bounds__(256) void k_gram(const float* __restrict__ C,
                                              double* __restrict__ GCC) {
  int ti = blockIdx.y, tj = blockIdx.x;
  if (ti < tj) return;
  __shared__ float As[64][33];
  __shared__ float Bs[64][33];
  int tid = threadIdx.x;
  int tr4 = (tid >> 4) * 4, tc4 = (tid & 15) * 4;
  double acc[4][4] = {};
  int i0 = ti * 64, j0 = tj * 64;
  for (int k0 = 0; k0 < LDC; k0 += 32) {
#pragma unroll
    for (int l = 0; l < 8; ++l) {
      int t = tid + l * 256;
      int rr = t >> 5, cc = t & 31;
      As[rr][cc] = C[(size_t)(i0 + rr) * LDC + k0 + cc];
      Bs[rr][cc] = C[(size_t)(j0 + rr) * LDC + k0 + cc];
    }
    __syncthreads();
#pragma unroll
    for (int kk = 0; kk < 32; ++kk) {
      double a[4], b[4];
#pragma unroll
      for (int i = 0; i < 4; ++i) a[i] = (double)As[tr4 + i][kk];
#pragma unroll
      for (int jx = 0; jx < 4; ++jx) b[jx] = (double)Bs[tc4 + jx][kk];
#pragma unroll
      for (int i = 0; i < 4; ++i)
#pragma unroll
        for (int jx = 0; jx < 4; ++jx) acc[i][jx] += a[i] * b[jx];
    }
    __syncthreads();
  }
#pragma unroll
  for (int i = 0; i < 4; ++i)
#pragma unroll
    for (int jx = 0; jx < 4; ++jx) {
      int gi = i0 + tr4 + i, gj = j0 + tc4 + jx;
      GCC[(size_t)gi * NCRP + gj] = acc[i][jx];
      if (ti != tj) GCC[(size_t)gj * NCRP + gi] = acc[i][jx];
    }
}

// ---- 3) G = GFF + (1e-6/d) I, padded with identity ----
__global__ __launch_bounds__(256) void k_copyG(const double* __restrict__ GCC,
                                               const float* __restrict__ q,
                                               const float* __restrict__ r,
                                               double* __restrict__ G) {
  int idx = blockIdx.x * 256 + threadIdx.x;
  int i = idx >> 10, j = idx & 1023;
  double v = (i < NFR && j < NFR) ? GCC[(size_t)i * NCRP + j] : 0.0;
  if (i == j) {
    if (i < NFR) v += 1e-6 / dweight(i, q, r);
    else v = 1.0;
  }
  G[idx] = v;
}

// ---- 4) TA rhs = GAF^T = F A^T (padded zeros) ----
__global__ __launch_bounds__(256) void k_copyTA(const double* __restrict__ GCC,
                                                double* __restrict__ TA) {
  int idx = blockIdx.x * 256 + threadIdx.x;
  int f = idx >> 9, a = idx & 511;
  TA[idx] = (f < NFR && a < NAR) ? GCC[(size_t)f * NCRP + 1000 + a] : 0.0;
}

// ---- fused potrf(64x64 diag block) + inv(L11) -> IDG ----
// Factor kept in T lower; inverse built column-parallel into T's UPPER triangle
// (iL[r][c] stored at T[c][r], diag in invd[]) to stay under 64 KB LDS.
__global__ __launch_bounds__(256) void k_potrf_inv(double* __restrict__ M, int ld, int k,
                                                   double* __restrict__ IDG) {
  __shared__ double T[64][65];
  __shared__ double invd[64];
  int tid = threadIdx.x;
#pragma unroll
  for (int l = 0; l < 16; ++l) {
    int t = tid + l * 256;
    T[t >> 6][t & 63] = M[(size_t)(k + (t >> 6)) * ld + k + (t & 63)];
  }
  __syncthreads();
  for (int c = 0; c < 64; ++c) {
    if (tid == 0) T[c][c] = sqrt(T[c][c]);
    __syncthreads();
    double piv = T[c][c];
    for (int rr = c + 1 + tid; rr < 64; rr += 256) T[rr][c] /= piv;
    __syncthreads();
    for (int t = tid; t < 64 * 64; t += 256) {
      int rr = t >> 6, jj = t & 63;
      if (rr > c && jj > c) T[rr][jj] -= T[rr][c] * T[jj][c];
    }
    __syncthreads();
  }
  // write L back (upper part of T holds junk; nothing reads G's upper)
#pragma unroll
  for (int l = 0; l < 16; ++l) {
    int t = tid + l * 256;
    M[(size_t)(k + (t >> 6)) * ld + k + (t & 63)] = T[t >> 6][t & 63];
  }
  __syncthreads();
  // inversion: thread c solves column c of inv(L)
  if (tid < 64) invd[tid] = 1.0 / T[tid][tid];
  __syncthreads();
  if (tid < 64) {
    int c = tid;
    for (int r = c + 1; r < 64; ++r) {
      double s = T[r][c] * invd[c];
      for (int j = c + 1; j < r; ++j) s += T[r][j] * T[c][j];  // T[c][j] = iL[j][c]
      T[c][r] = -s * invd[r];
    }
  }
  __syncthreads();
#pragma unroll
  for (int l = 0; l < 16; ++l) {
    int t = tid + l * 256;
    int r = t >> 6, c = t & 63;
    IDG[t] = (r < c) ? 0.0 : (r == c ? invd[r] : T[c][r]);
  }
}

// ---- chol panel solve as GEMM: L21 = A21 * iL^T (in-place, per-tile safe) ----
__global__ __launch_bounds__(256) void k_trsm_inv(double* __restrict__ M, int ld, int k,
                                                  const double* __restrict__ IDG) {
  __shared__ double As[64][33];
  __shared__ double Bs[32][65];
  int tid = threadIdx.x;
  int tr4 = (tid >> 4) * 4, tc4 = (tid & 15) * 4;
  int r0 = k + 64 + blockIdx.x * 64;
  double acc[4][4] = {};
  for (int k0 = 0; k0 < 64; k0 += 32) {
#pragma unroll
    for (int l = 0; l < 8; ++l) {
      int t = tid + l * 256;
      As[t >> 5][t & 31] = M[(size_t)(r0 + (t >> 5)) * ld + k + k0 + (t & 31)];
    }
#pragma unroll
    for (int l = 0; l < 8; ++l) {
      int t = tid + l * 256;
      int kk = t >> 6, cc = t & 63;
      Bs[kk][cc] = IDG[cc * 64 + k0 + kk];  // iL[c][k] -> B^T staging
    }
    __syncthreads();
#pragma unroll
    for (int kk = 0; kk < 32; ++kk) {
      double a[4], b[4];
#pragma unroll
      for (int i = 0; i < 4; ++i) a[i] = As[tr4 + i][kk];
#pragma unroll
      for (int jx = 0; jx < 4; ++jx) b[jx] = Bs[kk][tc4 + jx];
#pragma unroll
      for (int i = 0; i < 4; ++i)
#pragma unroll
        for (int jx = 0; jx < 4; ++jx) acc[i][jx] += a[i] * b[jx];
    }
    __syncthreads();
  }
#pragma unroll
  for (int i = 0; i < 4; ++i)
#pragma unroll
    for (int jx = 0; jx < 4; ++jx)
      M[(size_t)(r0 + tr4 + i) * ld + k + tc4 + jx] = acc[i][jx];
}

// ---- SYRK trailing update: A22 -= L21 * L21^T (lower tiles only) ----
__global__ __launch_bounds__(256) void k_chol_syrk(double* __restrict__ M, int ld, int k) {
  int ti = blockIdx.y, tj = blockIdx.x;
  if (ti < tj) return;
  __shared__ double Pa[64][33];
  __shared__ double Pb[64][33];
  int tid = threadIdx.x;
  int tr4 = (tid >> 4) * 4, tc4 = (tid & 15) * 4;
  int i0 = k + 64 + ti * 64, j0 = k + 64 + tj * 64;
  double acc[4][4] = {};
  for (int k0 = 0; k0 < 64; k0 += 32) {
#pragma unroll
    for (int l = 0; l < 8; ++l) {
      int t = tid + l * 256;
      int rr = t >> 5, cc = t & 31;
      Pa[rr][cc] = M[(size_t)(i0 + rr) * ld + k + k0 + cc];
      Pb[rr][cc] = M[(size_t)(j0 + rr) * ld + k + k0 + cc];
    }
    __syncthreads();
#pragma unroll
    for (int kk = 0; kk < 32; ++kk) {
      double a[4], b[4];
#pragma unroll
      for (int i = 0; i < 4; ++i) a[i] = Pa[tr4 + i][kk];
#pragma unroll
      for (int jx = 0; jx < 4; ++jx) b[jx] = Pb[tc4 + jx][kk];
#pragma unroll
      for (int i = 0; i < 4; ++i)
#pragma unroll
        for (int jx = 0; jx < 4; ++jx) acc[i][jx] += a[i] * b[jx];
    }
    __syncthreads();
  }
#pragma unroll
  for (int i = 0; i < 4; ++i)
#pragma unroll
    for (int jx = 0; jx < 4; ++jx)
      M[(size_t)(i0 + tr4 + i) * ld + j0 + tc4 + jx] -= acc[i][jx];
}

// ---- generic fp64 GEMM cores (64x64 C tile, 4x4 micro) ----
__device__ __forceinline__ void dgemm_nn_core(const double* __restrict__ A, int lda,
                                              const double* __restrict__ B, int ldb,
                                              double* __restrict__ C, int ldc,
                                              int kBeg, int kEnd, double alpha) {
  __shared__ double As[64][33];
  __shared__ double Bs[32][65];
  int tid = threadIdx.x;
  int tr4 = (tid >> 4) * 4, tc4 = (tid & 15) * 4;
  double acc[4][4] = {};
  for (int k0 = kBeg; k0 < kEnd; k0 += 32) {
#pragma unroll
    for (int l = 0; l < 8; ++l) {
      int t = tid + l * 256;
      As[t >> 5][t & 31] = A[(size_t)(t >> 5) * lda + k0 + (t & 31)];
    }
#pragma unroll
    for (int l = 0; l < 8; ++l) {
      int t = tid + l * 256;
      Bs[t >> 6][t & 63] = B[(size_t)(k0 + (t >> 6)) * ldb + (t & 63)];
    }
    __syncthreads();
#pragma unroll
    for (int kk = 0; kk < 32; ++kk) {
      double a[4], b[4];
#pragma unroll
      for (int i = 0; i < 4; ++i) a[i] = As[tr4 + i][kk];
#pragma unroll
      for (int jx = 0; jx < 4; ++jx) b[jx] = Bs[kk][tc4 + jx];
#pragma unroll
      for (int i = 0; i < 4; ++i)
#pragma unroll
        for (int jx = 0; jx < 4; ++jx) acc[i][jx] += a[i] * b[jx];
    }
    __syncthreads();
  }
#pragma unroll
  for (int i = 0; i < 4; ++i)
#pragma unroll
    for (int jx = 0; jx < 4; ++jx)
      C[(size_t)(tr4 + i) * ldc + tc4 + jx] = alpha * acc[i][jx];
}

__device__ __forceinline__ void dgemm_tn_core(const double* __restrict__ A, int lda,
                                              const double* __restrict__ B, int ldb,
                                              double* __restrict__ C, int ldc,
                                              int kBeg, int kEnd, double alpha) {
  __shared__ double Ls[32][65];
  __shared__ double Bs[32][65];
  int tid = threadIdx.x;
  int tr4 = (tid >> 4) * 4, tc4 = (tid & 15) * 4;
  double acc[4][4] = {};
  for (int k0 = kBeg; k0 < kEnd; k0 += 32) {
#pragma unroll
    for (int l = 0; l < 8; ++l) {
      int t = tid + l * 256;
      int jj = t >> 6, rr = t & 63;
      Ls[jj][rr] = A[(size_t)(k0 + jj) * lda + rr];
    }
#pragma unroll
    for (int l = 0; l < 8; ++l) {
      int t = tid + l * 256;
      Bs[t >> 6][t & 63] = B[(size_t)(k0 + (t >> 6)) * ldb + (t & 63)];
    }
    __syncthreads();
#pragma unroll
    for (int kk = 0; kk < 32; ++kk) {
      double a[4], b[4];
#pragma unroll
      for (int i = 0; i < 4; ++i) a[i] = Ls[kk][tr4 + i];
#pragma unroll
      for (int jx = 0; jx < 4; ++jx) b[jx] = Bs[kk][tc4 + jx];
#pragma unroll
      for (int i = 0; i < 4; ++i)
#pragma unroll
        for (int jx = 0; jx < 4; ++jx) acc[i][jx] += a[i] * b[jx];
    }
    __syncthreads();
  }
#pragma unroll
  for (int i = 0; i < 4; ++i)
#pragma unroll
    for (int jx = 0; jx < 4; ++jx)
      C[(size_t)(tr4 + i) * ldc + tc4 + jx] = alpha * acc[i][jx];
}

// C = alpha * A * B ; tri=1 -> A lower-triangular (k <= row-block)
__global__ __launch_bounds__(256) void k_dgemm_nn(const double* __restrict__ A, int lda,
                                                  const double* __restrict__ B, int ldb,
                                                  double* __restrict__ C, int ldc,
                                                  int K, int tri, double alpha) {
  int bi = blockIdx.y, bj = blockIdx.x;
  int kEnd = tri ? ((bi + 1) * 64 < K ? (bi + 1) * 64 : K) : K;
  dgemm_nn_core(A + (size_t)bi * 64 * lda, lda, B + bj * 64, ldb,
                C + (size_t)bi * 64 * ldc + bj * 64, ldc, 0, kEnd, alpha);
}

// C = alpha * A^T * B ; tri=1 -> A lower-triangular (k >= row-block)
__global__ __launch_bounds__(256) void k_dgemm_tn(const double* __restrict__ A, int lda,
                                                  const double* __restrict__ B, int ldb,
                                                  double* __restrict__ C, int ldc,
                                                  int K, int tri, double alpha) {
  int bi = blockIdx.y, bj = blockIdx.x;
  int kBeg = tri ? bi * 64 : 0;
  dgemm_tn_core(A + bi * 64, lda, B + bj * 64, ldb,
                C + (size_t)bi * 64 * ldc + bj * 64, ldc, kBeg, K, alpha);
}

// ---- iL assembly: diag-64 inverses in, zeros elsewhere ----
__global__ __launch_bounds__(256) void k_init_iL(double* __restrict__ iL, int nShift,
                                                 const double* __restrict__ IDIAG) {
  int idx = blockIdx.x * 256 + threadIdx.x;
  int n = 1 << nShift;
  int i = idx >> nShift, j = idx & (n - 1);
  int d = i >> 6;
  double v = 0.0;
  if ((j >> 6) == d) v = IDIAG[(size_t)d * 4096 + (i & 63) * 64 + (j & 63)];
  iL[idx] = v;
}

// ---- D&C inverse levels: T_p = L21 * iL11 ; then iL21 = -iL22 * T_p ----
__global__ __launch_bounds__(256) void k_ilv_tmp(const double* __restrict__ L, int ldl,
                                                 const double* __restrict__ iL, int ldi,
                                                 double* __restrict__ T, int half) {
  int p = blockIdx.z, bi = blockIdx.y, bj = blockIdx.x;
  int base = p * 2 * half;
  dgemm_nn_core(L + (size_t)(base + half + bi * 64) * ldl + base, ldl,
                iL + (size_t)base * ldi + base + bj * 64, ldi,
                T + (size_t)p * half * half + (size_t)bi * 64 * half + bj * 64, half,
                0, half, 1.0);
}

__global__ __launch_bounds__(256) void k_ilv_fin(double* __restrict__ iL, int ldi,
                                                 const double* __restrict__ T, int half) {
  int p = blockIdx.z, bi = blockIdx.y, bj = blockIdx.x;
  int base = p * 2 * half;
  dgemm_nn_core(iL + (size_t)(base + half + bi * 64) * ldi + base + half, ldi,
                T + (size_t)p * half * half + bj * 64, half,
                iL + (size_t)(base + half + bi * 64) * ldi + base + bj * 64, ldi,
                0, half, -1.0);
}

// ---- S = (GAA - GAF * TA) / (2*DELTA), identity-padded ----
__global__ __launch_bounds__(256) void k_buildS(const double* __restrict__ GCC,
                                                const double* __restrict__ TA,
                                                double* __restrict__ S) {
  __shared__ double Ga[64][33];
  __shared__ double Tb[32][65];
  int tid = threadIdx.x;
  int tr4 = (tid >> 4) * 4, tc4 = (tid & 15) * 4;
  int a0 = blockIdx.y * 64, b0 = blockIdx.x * 64;
  double acc[4][4] = {};
  for (int f0 = 0; f0 < NG; f0 += 32) {
#pragma unroll
    for (int l = 0; l < 8; ++l) {
      int t = tid + l * 256;
      int rr = t >> 5, cc = t & 31;
      Ga[rr][cc] = GCC[(size_t)(1000 + a0 + rr) * NCRP + f0 + cc];
    }
#pragma unroll
    for (int l = 0; l < 8; ++l) {
      int t = tid + l * 256;
      int rr = t >> 6, cc = t & 63;
      Tb[rr][cc] = TA[(size_t)(f0 + rr) * NS + b0 + cc];
    }
    __syncthreads();
#pragma unroll
    for (int kk = 0; kk < 32; ++kk) {
      double a[4], b[4];
#pragma unroll
      for (int i = 0; i < 4; ++i) a[i] = Ga[tr4 + i][kk];
#pragma unroll
      for (int jx = 0; jx < 4; ++jx) b[jx] = Tb[kk][tc4 + jx];
#pragma unroll
      for (int i = 0; i < 4; ++i)
#pragma unroll
        for (int jx = 0; jx < 4; ++jx) acc[i][jx] += a[i] * b[jx];
    }
    __syncthreads();
  }
#pragma unroll
  for (int i = 0; i < 4; ++i)
#pragma unroll
    for (int jx = 0; jx < 4; ++jx) {
      int a = a0 + tr4 + i, b = b0 + tc4 + jx;
      double v;
      if (a < NAR && b < NAR)
        v = (GCC[(size_t)(1000 + a) * NCRP + 1000 + b] - acc[i][jx]) * INVDP;
      else
        v = (a == b) ? 1.0 : 0.0;
      S[(size_t)a * NS + b] = v;
    }
}

// ---- X12 rhs = [TAq^T | I] ----
__global__ __launch_bounds__(256) void k_build_x12rhs(const double* __restrict__ TA,
                                                      double* __restrict__ X12) {
  int c = blockIdx.x * 256 + threadIdx.x;
  int a = blockIdx.y;
  if (c >= NXC) return;
  double v = 0.0;
  if (a < NAR) {
    if (c < 600) v = TA[(size_t)(400 + c) * NS + a];
    else if (c < 1106) v = (a == (c - 600)) ? 1.0 : 0.0;
  }
  X12[(size_t)a * NXC + c] = v;
}

// ---- Mraw = sign * (TA * X12) / (2 d_o)  (fp32 output) ----
__global__ __launch_bounds__(256) void k_gemm_M(const double* __restrict__ TA,
                                                const double* __restrict__ X12,
                                                const float* __restrict__ q,
                                                const float* __restrict__ r,
                                                float* __restrict__ Mraw) {
  __shared__ double Ga[64][33];
  __shared__ double Xb[32][65];
  int tid = threadIdx.x;
  int tr4 = (tid >> 4) * 4, tc4 = (tid & 15) * 4;
  int o0 = blockIdx.y * 64, c0 = blockIdx.x * 64;
  double acc[4][4] = {};
  for (int k0 = 0; k0 < NS; k0 += 32) {
#pragma unroll
    for (int l = 0; l < 8; ++l) {
      int t = tid + l * 256;
      int rr = t >> 5, cc = t & 31;
      Ga[rr][cc] = TA[(size_t)(o0 + rr) * NS + k0 + cc];
    }
#pragma unroll
    for (int l = 0; l < 8; ++l) {
      int t = tid + l * 256;
      int rr = t >> 6, cc = t & 63;
      Xb[rr][cc] = X12[(size_t)(k0 + rr) * NXC + c0 + cc];
    }
    __syncthreads();
#pragma unroll
    for (int kk = 0; kk < 32; ++kk) {
      double a[4], b[4];
#pragma unroll
      for (int i = 0; i < 4; ++i) a[i] = Ga[tr4 + i][kk];
#pragma unroll
      for (int jx = 0; jx < 4; ++jx) b[jx] = Xb[kk][tc4 + jx];
#pragma unroll
      for (int i = 0; i < 4; ++i)
#pragma unroll
        for (int jx = 0; jx < 4; ++jx) acc[i][jx] += a[i] * b[jx];
    }
    __syncthreads();
  }
#pragma unroll
  for (int i = 0; i < 4; ++i)
#pragma unroll
    for (int jx = 0; jx < 4; ++jx) {
      int o = o0 + tr4 + i, col = c0 + tc4 + jx;
      float v = 0.f;
      if (o < NFR) {
        double scale = 1.0 / (2.0 * dweight(o, q, r));
        double t = acc[i][jx] * scale;
        v = (float)((col < 600) ? -t : t);
      }
      Mraw[(size_t)o * NXC + col] = v;
    }
}

// ---- assemble final fp32 map: identity insert + ref_last fold ----
__global__ __launch_bounds__(256) void k_assemble_M(const float* __restrict__ Mraw,
                                                    float* __restrict__ Mall) {
  int j = blockIdx.x * 256 + threadIdx.x;
  int o = blockIdx.y;
  if (j >= LDMA) return;
  float v = 0.f;
  if (j < 600) {
    v = Mraw[(size_t)o * NXC + j];
    if (o == 400 + j) v += 1.0f;
    if (j >= 594) v += Mraw[(size_t)o * NXC + 1100 + (j - 594)];
  } else if (j < 1100) {
    v = Mraw[(size_t)o * NXC + j];
  }
  Mall[(size_t)o * LDMA + j] = v;
}

// ---- transpose batch inputs into IN_all [LDMA][NBATCH] ----
__global__ __launch_bounds__(256) void k_transpose_in(const float* __restrict__ ref,
                                                      const float* __restrict__ ui,
                                                      const float* __restrict__ yi,
                                                      float* __restrict__ INall) {
  __shared__ float t[32][33];
  int tx = threadIdx.x & 31, ty = threadIdx.x >> 5;  // 32 x 8
  int n0 = blockIdx.x * 32, j0 = blockIdx.y * 32;
#pragma unroll
  for (int p = 0; p < 4; ++p) {
    int nb = n0 + ty + p * 8;
    int j = j0 + tx;
    float v = 0.f;
    if (j < 600)        v = ref[(size_t)nb * 600 + j];
    else if (j < 800)   v = ui[(size_t)nb * 200 + (j - 600)];
    else if (j < 1100)  v = yi[(size_t)nb * 300 + (j - 800)];
    t[ty + p * 8][tx] = v;
  }
  __syncthreads();
#pragma unroll
  for (int p = 0; p < 4; ++p) {
    INall[(size_t)(j0 + ty + p * 8) * NBATCH + n0 + tx] = t[tx][ty + p * 8];
  }
}

// ---- final batch GEMM: OUT[1000][4096] = Mall[1000][1120] * INall[1120][4096] ----
__global__ __launch_bounds__(256) void k_gemm_out(const float* __restrict__ Mall,
                                                  const float* __restrict__ INall,
                                                  float* __restrict__ out) {
  __shared__ float As[32][132];
  __shared__ float Bs[32][132];
  int tid = threadIdx.x;
  int tr = tid >> 4, tc = tid & 15;
  int m0 = blockIdx.y * 128, n0 = blockIdx.x * 128;
  float acc[8][8] = {};
  for (int k0 = 0; k0 < LDMA; k0 += 32) {
#pragma unroll
    for (int l = 0; l < 16; ++l) {
      int t = tid + l * 256;
      int rr = t >> 5, cc = t & 31;
      As[cc][rr] = Mall[(size_t)(m0 + rr) * LDMA + k0 + cc];
    }
#pragma unroll
    for (int l = 0; l < 16; ++l) {
      int t = tid + l * 256;
      int rr = t >> 7, cc = t & 127;
      Bs[rr][cc] = INall[(size_t)(k0 + rr) * NBATCH + n0 + cc];
    }
    __syncthreads();
#pragma unroll
    for (int kk = 0; kk < 32; ++kk) {
      float4 a0 = *(const float4*)&As[kk][tr * 4];
      float4 a1 = *(const float4*)&As[kk][64 + tr * 4];
      float4 b0 = *(const float4*)&Bs[kk][tc * 4];
      float4 b1 = *(const float4*)&Bs[kk][64 + tc * 4];
      float av[8] = {a0.x, a0.y, a0.z, a0.w, a1.x, a1.y, a1.z, a1.w};
      float bv[8] = {b0.x, b0.y, b0.z, b0.w, b1.x, b1.y, b1.z, b1.w};
#pragma unroll
      for (int i = 0; i < 8; ++i)
#pragma unroll
        for (int jx = 0; jx < 8; ++jx) acc[i][jx] += av[i] * bv[jx];
    }
    __syncthreads();
  }
#pragma unroll
  for (int ih = 0; ih < 2; ++ih)
#pragma unroll
    for (int i = 0; i < 4; ++i) {
      int o = m0 + ih * 64 + tr * 4 + i;
      if (o < NOUT) {
#pragma unroll
        for (int jh = 0; jh < 2; ++jh) {
          float4 v = make_float4(acc[ih * 4 + i][jh * 4 + 0], acc[ih * 4 + i][jh * 4 + 1],
                                 acc[ih * 4 + i][jh * 4 + 2], acc[ih * 4 + i][jh * 4 + 3]);
          *(float4*)&out[(size_t)o * NBATCH + n0 + jh * 64 + tc * 4] = v;
        }
      }
    }
}

extern "C" void kernel_launch(void* const* d_in, const int* in_sizes, int n_in,
                              void* d_out, int out_size, void* d_ws, size_t ws_size,
                              hipStream_t stream) {
  const float* ud  = (const float*)d_in[0];
  const float* yd  = (const float*)d_in[1];
  const float* qv  = (const float*)d_in[2];
  const float* rv  = (const float*)d_in[3];
  const float* ref = (const float*)d_in[4];
  const float* ui  = (const float*)d_in[5];
  const float* yi  = (const float*)d_in[6];
  float* out = (float*)d_out;
  char* w = (char*)d_ws;

  float*  C    = (float*)(w + OFF_C);
  double* GCC  = (double*)(w + OFF_GCC);
  double* G    = (double*)(w + OFF_G);
  double* TA   = (double*)(w + OFF_TA);
  double* S    = (double*)(w + OFF_S);
  double* X12  = (double*)(w + OFF_X12);
  float*  MRAW = (float*)(w + OFF_MRAW);
  float*  MALL = (float*)(w + OFF_MALL);
  float*  INA  = (float*)(w + OFF_INALL);
  double* ILG  = (double*)(w + OFF_ILG);
  double* ILS  = (double*)(w + OFF_ILS);
  double* IDG  = (double*)(w + OFF_IDG);
  double* IDS  = (double*)(w + OFF_IDS);
  double* TB   = (double*)(w + OFF_TB);
  double* TINV = (double*)(w + OFF_TINV);
  double* XB   = (double*)(w + OFF_XB);

  // 1) Hankel blocks, Gram, G and T_A rhs
  k_build_C<<<dim3(8, NCRP), 256, 0, stream>>>(ud, yd, C);
  k_gram<<<dim3(24, 24), 256, 0, stream>>>(C, GCC);
  k_copyG<<<dim3(NG * NG / 256), 256, 0, stream>>>(GCC, qv, rv, G);
  k_copyTA<<<dim3(NG * NS / 256), 256, 0, stream>>>(GCC, TA);

  // 2) Cholesky of G (inv-diag trick; no serial TRSM kernels)
  for (int k = 0; k < NG; k += 64) {
    k_potrf_inv<<<1, 256, 0, stream>>>(G, NG, k, IDG + (size_t)(k >> 6) * 4096);
    int nb = (NG - k - 64) / 64;
    if (nb > 0) {
      k_trsm_inv<<<dim3(nb), 256, 0, stream>>>(G, NG, k, IDG + (size_t)(k >> 6) * 4096);
      k_chol_syrk<<<dim3(nb, nb), 256, 0, stream>>>(G, NG, k);
    }
  }

  // 3) iL_G via divide&conquer (log-depth), then T_A = iL^T iL GAF^T (2 GEMMs)
  k_init_iL<<<dim3(NG * NG / 256), 256, 0, stream>>>(ILG, 10, IDG);
  for (int lv = 0; lv < 4; ++lv) {
    int half = 64 << lv, pairs = NG / (2 * half);
    dim3 gt(half / 64, half / 64, pairs);
    k_ilv_tmp<<<gt, 256, 0, stream>>>(G, NG, ILG, NG, TINV, half);
    k_ilv_fin<<<gt, 256, 0, stream>>>(ILG, NG, TINV, half);
  }
  k_dgemm_nn<<<dim3(NS / 64, NG / 64), 256, 0, stream>>>(ILG, NG, TA, NS, TB, NS, NG, 1, 1.0);
  k_dgemm_tn<<<dim3(NS / 64, NG / 64), 256, 0, stream>>>(ILG, NG, TB, NS, TA, NS, NG, 1, 1.0);

  // 4) S and its Cholesky + iL_S
  k_buildS<<<dim3(8, 8), 256, 0, stream>>>(GCC, TA, S);
  for (int k = 0; k < NS; k += 64) {
    k_potrf_inv<<<1, 256, 0, stream>>>(S, NS, k, IDS + (size_t)(k >> 6) * 4096);
    int nb = (NS - k - 64) / 64;
    if (nb > 0) {
      k_trsm_inv<<<dim3(nb), 256, 0, stream>>>(S, NS, k, IDS + (size_t)(k >> 6) * 4096);
      k_chol_syrk<<<dim3(nb, nb), 256, 0, stream>>>(S, NS, k);
    }
  }
  k_init_iL<<<dim3(NS * NS / 256), 256, 0, stream>>>(ILS, 9, IDS);
  for (int lv = 0; lv < 3; ++lv) {
    int half = 64 << lv, pairs = NS / (2 * half);
    dim3 gt(half / 64, half / 64, pairs);
    k_ilv_tmp<<<gt, 256, 0, stream>>>(S, NS, ILS, NS, TINV, half);
    k_ilv_fin<<<gt, 256, 0, stream>>>(ILS, NS, TINV, half);
  }

  // 5) X12 = S^{-1} [TAq^T | I]  (2 GEMMs)
  k_build_x12rhs<<<dim3(5, NS), 256, 0, stream>>>(TA, X12);
  k_dgemm_nn<<<dim3(NXC / 64, NS / 64), 256, 0, stream>>>(ILS, NS, X12, NXC, XB, NXC, NS, 1, 1.0);
  k_dgemm_tn<<<dim3(NXC / 64, NS / 64), 256, 0, stream>>>(ILS, NS, XB, NXC, X12, NXC, NS, 1, 1.0);

  // 6) solution maps + batch GEMM
  k_gemm_M<<<dim3(NXC / 64, NG / 64), 256, 0, stream>>>(TA, X12, qv, rv, MRAW);
  k_assemble_M<<<dim3(5, NG), 256, 0, stream>>>(MRAW, MALL);
  k_transpose_in<<<dim3(NBATCH / 32, LDMA / 32), 256, 0, stream>>>(ref, ui, yi, INA);
  k_gemm_out<<<dim3(NBATCH / 128, NG / 128), 256, 0, stream>>>(MALL, INA, out);
}